// Round 1
// baseline (141.797 us; speedup 1.0000x reference)
//
#include <hip/hip_runtime.h>
#include <math.h>

#define HW1 (1024 * 1024)
#define WID 1024
#define HEI 1024

// Block-level reduce (wave shfl + LDS) then one atomicAdd per block.
__device__ __forceinline__ void block_atomic_add(float v, float* target, volatile float* sdata) {
#pragma unroll
    for (int off = 32; off > 0; off >>= 1)
        v += __shfl_down(v, off, 64);
    const int lane = threadIdx.x & 63;
    const int wv   = threadIdx.x >> 6;
    if (lane == 0) sdata[wv] = v;
    __syncthreads();
    if (threadIdx.x == 0) {
        float s = 0.f;
        const int nw = blockDim.x >> 6;
        for (int i = 0; i < nw; ++i) s += sdata[i];
        atomicAdd(target, s);
    }
    __syncthreads();
}

// Main pass: one thread owns a 4x4 pixel block.
//  - r_loss partial: sum |a-b| over 8*3*16 elements
//  - c_loss: per-channel batch norms + dot for 4 pixels (x within float4), arccos
//  - pooled diff (targets - preds) written to ws (one pool cell per thread)
__global__ __launch_bounds__(256) void k_main(const float* __restrict__ A,
                                              const float* __restrict__ B,
                                              float* __restrict__ pool,
                                              float* __restrict__ acc) {
    const int gx = threadIdx.x;  // 0..255 pool-x
    const int gy = blockIdx.x;   // 0..255 pool-y
    const int px = gx * 4;
    const int py = gy * 4;

    float na2[12], nb2[12], dt[12];  // [c*4 + xi]
#pragma unroll
    for (int i = 0; i < 12; ++i) { na2[i] = 0.f; nb2[i] = 0.f; dt[i] = 0.f; }
    float r_sum = 0.f;

    for (int b = 0; b < 8; ++b) {
#pragma unroll
        for (int c = 0; c < 3; ++c) {
            const size_t base = (size_t)(b * 3 + c) * HW1 + (size_t)py * WID + px;
            const float* Ap = A + base;
            const float* Bp = B + base;
            float pd = 0.f;
#pragma unroll
            for (int yy = 0; yy < 4; ++yy) {
                const float4 a4 = *reinterpret_cast<const float4*>(Ap + yy * WID);
                const float4 b4 = *reinterpret_cast<const float4*>(Bp + yy * WID);
                {
                    float a = a4.x, t = b4.x;
                    na2[c * 4 + 0] += a * a; nb2[c * 4 + 0] += t * t; dt[c * 4 + 0] += a * t;
                    r_sum += fabsf(a - t); pd += t - a;
                }
                {
                    float a = a4.y, t = b4.y;
                    na2[c * 4 + 1] += a * a; nb2[c * 4 + 1] += t * t; dt[c * 4 + 1] += a * t;
                    r_sum += fabsf(a - t); pd += t - a;
                }
                {
                    float a = a4.z, t = b4.z;
                    na2[c * 4 + 2] += a * a; nb2[c * 4 + 2] += t * t; dt[c * 4 + 2] += a * t;
                    r_sum += fabsf(a - t); pd += t - a;
                }
                {
                    float a = a4.w, t = b4.w;
                    na2[c * 4 + 3] += a * a; nb2[c * 4 + 3] += t * t; dt[c * 4 + 3] += a * t;
                    r_sum += fabsf(a - t); pd += t - a;
                }
            }
            pool[((b * 3 + c) * 256 + gy) * 256 + gx] = pd * (1.0f / 16.0f);
        }
    }

    float c_sum = 0.f;
#pragma unroll
    for (int xi = 0; xi < 4; ++xi) {
        float cs = 0.f;
#pragma unroll
        for (int c = 0; c < 3; ++c) {
            float na = fmaxf(sqrtf(na2[c * 4 + xi]), 1e-12f);
            float nb = fmaxf(sqrtf(nb2[c * 4 + xi]), 1e-12f);
            cs += dt[c * 4 + xi] / (na * nb);
        }
        cs = fminf(fmaxf(cs, -1.0f + 1e-7f), 1.0f - 1e-7f);
        c_sum += acosf(cs);
    }

    __shared__ float s1[4], s2[4];
    block_atomic_add(r_sum, acc + 0, s1);
    block_atomic_add(c_sum, acc + 1, s2);
}

// Sobel |grad| sum on batch-0 images (cross-correlation, zero-padded).
// Each thread computes 4 consecutive x outputs; taps hit L1/L2.
__global__ __launch_bounds__(256) void k_sobel(const float* __restrict__ A,
                                               const float* __restrict__ B,
                                               float* __restrict__ acc) {
    const int t   = blockIdx.x * 256 + threadIdx.x;  // 0 .. 786431
    const int x0  = (t & 255) * 4;
    const int rem = t >> 8;       // 0..3071
    const int y   = rem & 1023;
    const int c   = rem >> 10;    // 0..2

    const float* Ap = A + (size_t)c * HW1;
    const float* Bp = B + (size_t)c * HW1;

    auto d = [&](int yy, int xx) -> float {
        if (yy < 0 || yy >= HEI || xx < 0 || xx >= WID) return 0.f;
        const int off = yy * WID + xx;
        return Ap[off] - Bp[off];
    };

    float s = 0.f;
#pragma unroll
    for (int i = 0; i < 4; ++i) {
        const int x = x0 + i;
        float g = (d(y - 1, x - 1) + 2.f * d(y, x - 1) + d(y + 1, x - 1))
                - (d(y - 1, x + 1) + 2.f * d(y, x + 1) + d(y + 1, x + 1));
        s += fabsf(g);
    }

    __shared__ float sd[4];
    block_atomic_add(s, acc + 2, sd);
}

// Spatial-consistency loss from pooled diff array P[24][256][256].
__global__ __launch_bounds__(256) void k_spa(const float* __restrict__ P,
                                             float* __restrict__ acc) {
    const int t = blockIdx.x * 256 + threadIdx.x;  // 0 .. 524287
    const int x = t & 255;
    const int y = (t >> 8) & 255;
    const int b = t >> 16;  // 0..7

    const float* Rr = P + (size_t)(b * 3 + 0) * 65536 + y * 256;
    const float* Gg = P + (size_t)(b * 3 + 1) * 65536 + y * 256;
    const float* Bb = P + (size_t)(b * 3 + 2) * 65536 + y * 256;

    const float g  = Gg[x];
    const float gl = (x > 0)   ? Gg[x - 1] : 0.f;
    const float gr = (x < 255) ? Gg[x + 1] : 0.f;
    const float d0 = g - gl;
    const float d1 = g - gr;
    const float d2 = g - Rr[x];
    const float d3 = g - Bb[x];
    float s = d0 * d0 + d1 * d1 + d2 * d2 + d3 * d3;

    __shared__ float sd[4];
    block_atomic_add(s, acc + 3, sd);
}

// Combine: out = W_C*c + W_R*r + W_P*p + W_S*s
__global__ void k_final(const float* __restrict__ acc, float* __restrict__ out) {
    const float r = acc[0] * (1.0f / 25165824.0f);  // mean over 8*3*1024*1024
    const float c = acc[1];
    const float s = acc[2];
    const float p = acc[3] * (1.0f / 524288.0f);    // mean over 8*256*256
    out[0] = 0.5f * c + 1.0f * r + 1.0f * p + 0.1f * s;
}

extern "C" void kernel_launch(void* const* d_in, const int* in_sizes, int n_in,
                              void* d_out, int out_size, void* d_ws, size_t ws_size,
                              hipStream_t stream) {
    const float* A = (const float*)d_in[0];  // predictions
    const float* B = (const float*)d_in[1];  // targets
    float* acc  = (float*)d_ws;              // 4 accumulators (+ padding)
    float* pool = (float*)d_ws + 64;         // 8*3*256*256 floats = 6.29 MB

    hipMemsetAsync(d_ws, 0, 64 * sizeof(float), stream);

    hipLaunchKernelGGL(k_main,  dim3(256),  dim3(256), 0, stream, A, B, pool, acc);
    hipLaunchKernelGGL(k_sobel, dim3(3072), dim3(256), 0, stream, A, B, acc);
    hipLaunchKernelGGL(k_spa,   dim3(2048), dim3(256), 0, stream, pool, acc);
    hipLaunchKernelGGL(k_final, dim3(1),    dim3(1),   0, stream, acc, (float*)d_out);
}